// Round 22
// baseline (53.707 us; speedup 1.0000x reference)
//
#include <hip/hip_runtime.h>
#include <math.h>

#define NROWS 4096
#define DDIM  64
#define NBINS 2048
#define NSHARD 8
#define HIST_W    0.25f    // 2048 bins over [0, 512)
#define HIST_INVW 4.0f

// ws layout (bytes):
// [0      .. 65536  )  hist8[8][2048] u32        -- zeroed by prep each call
// [65536  .. 81920  )  x_sq (4096 f32)
// [81920  .. 98304  )  y_sq (4096 f32)
// [131072 .. 2228224)  Xh, Xl, Yh, Yl (each 4096x64 bf16 = 512 KB)
//
// Fragment-major bf16 layout: (row,k) -> ((row>>4)*8 + (k>>3))*128 + (row&15)*8 + (k&7)
// => one MFMA fragment (16 rows x 32 k) = base + lane*8 shorts (coalesced 1 KB wave load).
//
// HW lessons carried:
//  - R12: prior-launch data is coherent across the kernel boundary -> plain loads.
//  - R14/R16/R19: write BW scales with RESIDENT BLOCKS/CU (1 blk=1.0 TB/s,
//    2 blk=2.7 TB/s) -> latency-bound, not HBM-bound. LDS tile capped us at 2.
//  - R10: direct swapped-MFMA stores amplified 2.15x — but ONLY tested with
//    NT (bypasses L2, 64B granule). R22 experiment: direct stores + PLAIN
//    (L2 merges the two 64B halves of each 128B line) + 4 blocks/CU.
//  - R17/R18/R20/R21: nulls/confounds on vmcnt order, NT-vs-plain (LDS path),
//    prep staging, run-length.

typedef __attribute__((ext_vector_type(8))) short short8;
typedef __attribute__((ext_vector_type(4))) float f32x4;

__device__ inline unsigned short f2bf(float f) {           // RNE f32 -> bf16 bits
    unsigned u = __builtin_bit_cast(unsigned, f);
    u += 0x7FFFu + ((u >> 16) & 1u);
    return (unsigned short)(u >> 16);
}
__device__ inline float bf2f(unsigned short h) {
    unsigned u = ((unsigned)h) << 16;
    return __builtin_bit_cast(float, u);
}

__global__ void prep_kernel(const float* __restrict__ X, const float* __restrict__ Y,
                            unsigned short* __restrict__ Xh, unsigned short* __restrict__ Xl,
                            unsigned short* __restrict__ Yh, unsigned short* __restrict__ Yl,
                            float* __restrict__ x_sq, float* __restrict__ y_sq,
                            unsigned* __restrict__ hist8) {
    int gid = blockIdx.x * blockDim.x + threadIdx.x;       // 0..65535
    if (gid < NSHARD * NBINS) hist8[gid] = 0u;
    int row = gid >> 3, kb = gid & 7;                      // one row-octet per thread
    int r = (row < NROWS) ? row : row - NROWS;
    const float* src = ((row < NROWS) ? X : Y) + (size_t)r * DDIM + kb * 8;
    unsigned short* dh = (row < NROWS) ? Xh : Yh;
    unsigned short* dl = (row < NROWS) ? Xl : Yl;
    float* sq = (row < NROWS) ? x_sq : y_sq;

    float4 a = *(const float4*)src;
    float4 b = *(const float4*)(src + 4);
    float v[8] = {a.x, a.y, a.z, a.w, b.x, b.y, b.z, b.w};
    short8 vh, vl;
    float s = 0.f;
#pragma unroll
    for (int j = 0; j < 8; ++j) {
        s = fmaf(v[j], v[j], s);
        unsigned short h = f2bf(v[j]);
        vh[j] = (short)h;
        vl[j] = (short)f2bf(v[j] - bf2f(h));
    }
    s += __shfl_xor(s, 1);
    s += __shfl_xor(s, 2);
    s += __shfl_xor(s, 4);
    if (kb == 0) sq[r] = s;
    size_t o = ((size_t)(r >> 4) * 8 + kb) * 128 + (size_t)(r & 15) * 8;
    *(short8*)(dh + o) = vh;
    *(short8*)(dl + o) = vl;
}

// One wave's 64x64 Xh*Yh tile (hist use): all 16 fragment loads upfront.
template <typename F>
__device__ inline void compute_tile_hh(const unsigned short* __restrict__ Xh,
                                       const unsigned short* __restrict__ Yh,
                                       int i0, int j0, size_t la, F&& body) {
    const int pa0 = i0 >> 4, pb0 = j0 >> 4;
    short8 fxh[8], fyh[8];
#pragma unroll
    for (int kh = 0; kh < 2; ++kh)
#pragma unroll
        for (int g = 0; g < 4; ++g) {
            fxh[kh * 4 + g] = *(const short8*)(Xh + ((size_t)(pa0 + g) * 8 + kh * 4) * 128 + la);
            fyh[kh * 4 + g] = *(const short8*)(Yh + ((size_t)(pb0 + g) * 8 + kh * 4) * 128 + la);
        }
    f32x4 acc[4][4];
#pragma unroll
    for (int r = 0; r < 4; ++r)
#pragma unroll
        for (int c = 0; c < 4; ++c) acc[r][c] = (f32x4){0.f, 0.f, 0.f, 0.f};
#pragma unroll
    for (int kh = 0; kh < 2; ++kh)
#pragma unroll
        for (int r = 0; r < 4; ++r)
#pragma unroll
            for (int c = 0; c < 4; ++c)
                acc[r][c] = __builtin_amdgcn_mfma_f32_16x16x32_bf16(fxh[kh * 4 + r], fyh[kh * 4 + c], acc[r][c], 0, 0, 0);
    body(acc);
}

// Histogram pass: 128 blocks (4x32); each block does ONE 128x128 tile with a
// rotating column offset so every row and column is sampled 512x (1/8 of the
// matrix, 2.1M samples). Xh*Yh only. LDS-binned, then flushed into one of 8
// sharded global histograms (16-way block contention — cheap).
__launch_bounds__(256, 2)
__global__ void hist_kernel(const unsigned short* __restrict__ Xh,
                            const unsigned short* __restrict__ Yh,
                            const float* __restrict__ x_sq, const float* __restrict__ y_sq,
                            unsigned* __restrict__ hist8) {
    __shared__ unsigned lhist[NBINS];
    const int t    = threadIdx.x;
    const int wave = t >> 6;
    const int lane = t & 63;
    const int fr = lane & 15;
    const int rb = (lane >> 4) * 4;
    const size_t la = (size_t)lane * 8;
    const int i0 = blockIdx.y * 128 + (wave >> 1) * 64;
    const int j0 = blockIdx.x * 1024 + (blockIdx.y & 7) * 128 + (wave & 1) * 64;

#pragma unroll
    for (int i = 0; i < NBINS / 256; ++i) lhist[t + i * 256] = 0u;
    __syncthreads();

    float xsv[4][4];
#pragma unroll
    for (int r = 0; r < 4; ++r)
#pragma unroll
        for (int q = 0; q < 4; ++q) xsv[r][q] = x_sq[i0 + r * 16 + rb + q];
    float ysv[4];
#pragma unroll
    for (int c = 0; c < 4; ++c) ysv[c] = y_sq[j0 + c * 16 + fr];

    compute_tile_hh(Xh, Yh, i0, j0, la, [&](f32x4 (&acc)[4][4]) {
#pragma unroll
        for (int r = 0; r < 4; ++r)
#pragma unroll
            for (int q = 0; q < 4; ++q) {
                float xs = xsv[r][q];
#pragma unroll
                for (int c = 0; c < 4; ++c) {
                    float dv = fmaf(-2.f, acc[r][c][q], xs + ysv[c]);
                    int idx = (int)(dv * HIST_INVW);
                    idx = idx < 0 ? 0 : (idx > NBINS - 1 ? NBINS - 1 : idx);
                    atomicAdd(&lhist[idx], 1u);
                }
            }
    });
    __syncthreads();
    unsigned* dst = hist8 + (size_t)((blockIdx.y * gridDim.x + blockIdx.x) & (NSHARD - 1)) * NBINS;
#pragma unroll
    for (int i = 0; i < NBINS / 256; ++i) {
        unsigned cv = lhist[t + i * 256];
        if (cv) atomicAdd(&dst[t + i * 256], cv);
    }
}

// Exp-write pass: grid (32,32) = 1024 blocks, 4 blocks/CU (LDS only 9.3KB —
// no transpose tile). Operand-SWAPPED MFMA (R10, correctness-verified):
// lane's acc[r][c] f32x4 = 4 CONTIGUOUS output cols; 4 lanes with equal fr
// cover a 64B row segment; the adjacent c instruction writes the other 64B
// half of each 128B line and PLAIN stores let L2 dirty-merge them (the
// untested cell — R10 used NT which bypasses L2). Local median per block.
__launch_bounds__(256, 4)
__global__ void write_kernel(const unsigned short* __restrict__ Xh, const unsigned short* __restrict__ Xl,
                             const unsigned short* __restrict__ Yh, const unsigned short* __restrict__ Yl,
                             const float* __restrict__ x_sq, const float* __restrict__ y_sq,
                             const unsigned* __restrict__ hist8, float* __restrict__ out) {
    __shared__ unsigned cnt[NBINS];     // 8 KB
    __shared__ unsigned tsum[256];      // 1 KB
    __shared__ float vmed[2];
    __shared__ float s_cc;
    const int t    = threadIdx.x;
    const int wave = t >> 6;
    const int lane = t & 63;
    const int fr = lane & 15;
    const int rb = (lane >> 4) * 4;
    const size_t la = (size_t)lane * 8;
    const int i0 = blockIdx.y * 128 + (wave >> 1) * 64;
    const int j0 = blockIdx.x * 128 + (wave & 1) * 64;

    {   // ---- local median: sum 8 shards (plain, coalesced, L2-broadcast),
        // scan, derive cc. All blocks in parallel, no signaling.
        unsigned s = 0;
#pragma unroll
        for (int i = 0; i < NBINS / 256; ++i) {
            unsigned b = t * (NBINS / 256) + i;
            unsigned cv = 0;
#pragma unroll
            for (int sd = 0; sd < NSHARD; ++sd)
                cv += hist8[sd * NBINS + b];       // prior-kernel data: plain loads
            cnt[b] = cv;
            s += cv;
        }
        tsum[t] = s;
        __syncthreads();
        for (int off = 1; off < 256; off <<= 1) {
            unsigned v = (t >= off) ? tsum[t - off] : 0u;
            __syncthreads();
            tsum[t] += v;
            __syncthreads();
        }
        unsigned cum = (t == 0) ? 0u : tsum[t - 1];
        unsigned total = tsum[255];
        const unsigned K2 = total >> 1;            // torch median ranks
        const unsigned K1 = K2 - 1u + (total & 1u);
        for (int i = 0; i < NBINS / 256; ++i) {
            int b = t * (NBINS / 256) + i;
            unsigned cv = cnt[b];
            if (cv) {
                if (K1 >= cum && (K1 - cum) < cv)
                    vmed[0] = ((float)b + ((float)(K1 - cum) + 0.5f) / (float)cv) * HIST_W;
                if (K2 >= cum && (K2 - cum) < cv)
                    vmed[1] = ((float)b + ((float)(K2 - cum) + 0.5f) / (float)cv) * HIST_W;
            }
            cum += cv;
        }
        __syncthreads();
        if (t == 0) {
            double med   = 0.5 * ((double)vmed[0] + (double)vmed[1]);
            double gamma = 8.317766166719343 / med;               // ln(4096)/med
            s_cc = (float)(-gamma * 1.4426950408889634);          // -gamma*log2(e)
        }
        __syncthreads();
    }
    const float cc = s_cc;

    const int pa0 = i0 >> 4, pb0 = j0 >> 4;

    // fragment loads (upfront, one latency exposure)
    short8 fxh[8], fxl[8], fyh[8], fyl[8];
#pragma unroll
    for (int kh = 0; kh < 2; ++kh)
#pragma unroll
        for (int g = 0; g < 4; ++g) {
            const size_t ao = ((size_t)(pa0 + g) * 8 + kh * 4) * 128 + la;
            const size_t bo = ((size_t)(pb0 + g) * 8 + kh * 4) * 128 + la;
            fxh[kh * 4 + g] = *(const short8*)(Xh + ao);
            fxl[kh * 4 + g] = *(const short8*)(Xl + ao);
            fyh[kh * 4 + g] = *(const short8*)(Yh + bo);
            fyl[kh * 4 + g] = *(const short8*)(Yl + bo);
        }

    // SWAPPED MFMA: D-col = lane&15 = X-row, D-row = (lane>>4)*4+q = Y-col.
    f32x4 acc[4][4];
#pragma unroll
    for (int r = 0; r < 4; ++r)
#pragma unroll
        for (int c = 0; c < 4; ++c) acc[r][c] = (f32x4){0.f, 0.f, 0.f, 0.f};
#pragma unroll
    for (int kh = 0; kh < 2; ++kh)
#pragma unroll
        for (int r = 0; r < 4; ++r)
#pragma unroll
            for (int c = 0; c < 4; ++c) {
                acc[r][c] = __builtin_amdgcn_mfma_f32_16x16x32_bf16(fyh[kh * 4 + c], fxh[kh * 4 + r], acc[r][c], 0, 0, 0);
                acc[r][c] = __builtin_amdgcn_mfma_f32_16x16x32_bf16(fyh[kh * 4 + c], fxl[kh * 4 + r], acc[r][c], 0, 0, 0);
                acc[r][c] = __builtin_amdgcn_mfma_f32_16x16x32_bf16(fyl[kh * 4 + c], fxh[kh * 4 + r], acc[r][c], 0, 0, 0);
                acc[r][c] = __builtin_amdgcn_mfma_f32_16x16x32_bf16(fyl[kh * 4 + c], fxl[kh * 4 + r], acc[r][c], 0, 0, 0);
            }

    float xsv[4];
#pragma unroll
    for (int r = 0; r < 4; ++r) xsv[r] = x_sq[i0 + r * 16 + fr];
    f32x4 ysq4[4];
#pragma unroll
    for (int c = 0; c < 4; ++c) ysq4[c] = *(const f32x4*)&y_sq[j0 + c * 16 + rb];

#pragma unroll
    for (int r = 0; r < 4; ++r) {
        const int row = i0 + r * 16 + fr;
        const float xs = xsv[r];
#pragma unroll
        for (int c = 0; c < 4; ++c) {
            f32x4 v;
#pragma unroll
            for (int q = 0; q < 4; ++q) {
                float dv = fmaf(-2.f, acc[r][c][q], xs + ysq4[c][q]);
                v[q] = __builtin_amdgcn_exp2f(cc * dv);
            }
            // PLAIN store: 64B row segments land in L2; adjacent c's store
            // fills the other half of the 128B line -> one HBM writeback.
            f32x4* po = (f32x4*)(out + (size_t)row * NROWS + j0 + c * 16 + rb);
            *po = v;
        }
    }
}

extern "C" void kernel_launch(void* const* d_in, const int* in_sizes, int n_in,
                              void* d_out, int out_size, void* d_ws, size_t ws_size,
                              hipStream_t stream) {
    const float* X = (const float*)d_in[0];
    const float* Y = (const float*)d_in[1];
    float* out = (float*)d_out;

    unsigned* hist8    = (unsigned*)d_ws;
    float* x_sq        = (float*)((char*)d_ws + 65536);
    float* y_sq        = (float*)((char*)d_ws + 81920);
    unsigned short* Xh = (unsigned short*)((char*)d_ws + 131072);
    unsigned short* Xl = Xh + (size_t)NROWS * DDIM;
    unsigned short* Yh = Xl + (size_t)NROWS * DDIM;
    unsigned short* Yl = Yh + (size_t)NROWS * DDIM;

    prep_kernel<<<256, 256, 0, stream>>>(X, Y, Xh, Xl, Yh, Yl, x_sq, y_sq, hist8);
    hist_kernel<<<dim3(4, 32), 256, 0, stream>>>(Xh, Yh, x_sq, y_sq, hist8);
    write_kernel<<<dim3(32, 32), 256, 0, stream>>>(Xh, Xl, Yh, Yl, x_sq, y_sq, hist8, out);
}

// Round 23
// 34.189 us; speedup vs baseline: 1.5709x; 1.5709x over previous
//
#include <hip/hip_runtime.h>
#include <math.h>

#define NROWS 4096
#define DDIM  64
#define NBINS 2048
#define NSHARD 8
#define HIST_W    0.25f    // 2048 bins over [0, 512)
#define HIST_INVW 4.0f

// ws layout (bytes):
// [0      .. 65536  )  hist8[8][2048] u32        -- zeroed by prep each call
// [65536  .. 81920  )  x_sq (4096 f32)
// [81920  .. 98304  )  y_sq (4096 f32)
// [131072 .. 2228224)  Xh, Xl, Yh, Yl (each 4096x64 bf16 = 512 KB)
//
// Fragment-major bf16 layout: (row,k) -> ((row>>4)*8 + (k>>3))*128 + (row&15)*8 + (k&7)
// => one MFMA fragment (16 rows x 32 k) = base + lane*8 shorts (coalesced 1 KB wave load).
//
// HW lessons carried (final set):
//  - R4/R10/R22: wave stores must cover full 128B lines per instruction; the
//    LDS-transpose epilogue is mandatory (direct 64B-segment stores amplify,
//    NT or plain).
//  - R12: prior-launch data is coherent across the kernel boundary -> plain
//    loads; atomics only for intra-kernel signals.
//  - R14/R15/R16: write needs parallelism AND pipelining: 2 resident blocks
//    x 2 tiles each (R16/R19 = 35us). 1 block/CU = 69us (R14).
//  - R17-R22: seven refuted/confounded store-side theories (vmcnt order,
//    NT-vs-plain, signaling storm, run-length x2, direct-store, waves/CU).
//  - R23: XCD 2D-chunk swizzle in write — default round-robin makes each
//    XCD's L2 touch ALL X rows (FETCH 31MB vs 2MB unique, R22 PMC); chunked
//    mapping gives each XCD 8x8 blocks (~0.75MB unique).

typedef __attribute__((ext_vector_type(8))) short short8;
typedef __attribute__((ext_vector_type(4))) float f32x4;

__device__ inline unsigned short f2bf(float f) {           // RNE f32 -> bf16 bits
    unsigned u = __builtin_bit_cast(unsigned, f);
    u += 0x7FFFu + ((u >> 16) & 1u);
    return (unsigned short)(u >> 16);
}
__device__ inline float bf2f(unsigned short h) {
    unsigned u = ((unsigned)h) << 16;
    return __builtin_bit_cast(float, u);
}

__global__ void prep_kernel(const float* __restrict__ X, const float* __restrict__ Y,
                            unsigned short* __restrict__ Xh, unsigned short* __restrict__ Xl,
                            unsigned short* __restrict__ Yh, unsigned short* __restrict__ Yl,
                            float* __restrict__ x_sq, float* __restrict__ y_sq,
                            unsigned* __restrict__ hist8) {
    int gid = blockIdx.x * blockDim.x + threadIdx.x;       // 0..65535
    if (gid < NSHARD * NBINS) hist8[gid] = 0u;
    int row = gid >> 3, kb = gid & 7;                      // one row-octet per thread
    int r = (row < NROWS) ? row : row - NROWS;
    const float* src = ((row < NROWS) ? X : Y) + (size_t)r * DDIM + kb * 8;
    unsigned short* dh = (row < NROWS) ? Xh : Yh;
    unsigned short* dl = (row < NROWS) ? Xl : Yl;
    float* sq = (row < NROWS) ? x_sq : y_sq;

    float4 a = *(const float4*)src;
    float4 b = *(const float4*)(src + 4);
    float v[8] = {a.x, a.y, a.z, a.w, b.x, b.y, b.z, b.w};
    short8 vh, vl;
    float s = 0.f;
#pragma unroll
    for (int j = 0; j < 8; ++j) {
        s = fmaf(v[j], v[j], s);
        unsigned short h = f2bf(v[j]);
        vh[j] = (short)h;
        vl[j] = (short)f2bf(v[j] - bf2f(h));
    }
    s += __shfl_xor(s, 1);
    s += __shfl_xor(s, 2);
    s += __shfl_xor(s, 4);
    if (kb == 0) sq[r] = s;
    size_t o = ((size_t)(r >> 4) * 8 + kb) * 128 + (size_t)(r & 15) * 8;
    *(short8*)(dh + o) = vh;
    *(short8*)(dl + o) = vl;
}

// One wave's 64x64 Xh*Yh tile (hist use): all 16 fragment loads upfront.
template <typename F>
__device__ inline void compute_tile_hh(const unsigned short* __restrict__ Xh,
                                       const unsigned short* __restrict__ Yh,
                                       int i0, int j0, size_t la, F&& body) {
    const int pa0 = i0 >> 4, pb0 = j0 >> 4;
    short8 fxh[8], fyh[8];
#pragma unroll
    for (int kh = 0; kh < 2; ++kh)
#pragma unroll
        for (int g = 0; g < 4; ++g) {
            fxh[kh * 4 + g] = *(const short8*)(Xh + ((size_t)(pa0 + g) * 8 + kh * 4) * 128 + la);
            fyh[kh * 4 + g] = *(const short8*)(Yh + ((size_t)(pb0 + g) * 8 + kh * 4) * 128 + la);
        }
    f32x4 acc[4][4];
#pragma unroll
    for (int r = 0; r < 4; ++r)
#pragma unroll
        for (int c = 0; c < 4; ++c) acc[r][c] = (f32x4){0.f, 0.f, 0.f, 0.f};
#pragma unroll
    for (int kh = 0; kh < 2; ++kh)
#pragma unroll
        for (int r = 0; r < 4; ++r)
#pragma unroll
            for (int c = 0; c < 4; ++c)
                acc[r][c] = __builtin_amdgcn_mfma_f32_16x16x32_bf16(fxh[kh * 4 + r], fyh[kh * 4 + c], acc[r][c], 0, 0, 0);
    body(acc);
}

// Histogram pass: 128 blocks (4x32); each block does ONE 128x128 tile with a
// rotating column offset so every row and column is sampled 512x (1/8 of the
// matrix, 2.1M samples). Xh*Yh only. LDS-binned, then flushed into one of 8
// sharded global histograms (16-way block contention — cheap).
__launch_bounds__(256, 2)
__global__ void hist_kernel(const unsigned short* __restrict__ Xh,
                            const unsigned short* __restrict__ Yh,
                            const float* __restrict__ x_sq, const float* __restrict__ y_sq,
                            unsigned* __restrict__ hist8) {
    __shared__ unsigned lhist[NBINS];
    const int t    = threadIdx.x;
    const int wave = t >> 6;
    const int lane = t & 63;
    const int fr = lane & 15;
    const int rb = (lane >> 4) * 4;
    const size_t la = (size_t)lane * 8;
    const int i0 = blockIdx.y * 128 + (wave >> 1) * 64;
    const int j0 = blockIdx.x * 1024 + (blockIdx.y & 7) * 128 + (wave & 1) * 64;

#pragma unroll
    for (int i = 0; i < NBINS / 256; ++i) lhist[t + i * 256] = 0u;
    __syncthreads();

    float xsv[4][4];
#pragma unroll
    for (int r = 0; r < 4; ++r)
#pragma unroll
        for (int q = 0; q < 4; ++q) xsv[r][q] = x_sq[i0 + r * 16 + rb + q];
    float ysv[4];
#pragma unroll
    for (int c = 0; c < 4; ++c) ysv[c] = y_sq[j0 + c * 16 + fr];

    compute_tile_hh(Xh, Yh, i0, j0, la, [&](f32x4 (&acc)[4][4]) {
#pragma unroll
        for (int r = 0; r < 4; ++r)
#pragma unroll
            for (int q = 0; q < 4; ++q) {
                float xs = xsv[r][q];
#pragma unroll
                for (int c = 0; c < 4; ++c) {
                    float dv = fmaf(-2.f, acc[r][c][q], xs + ysv[c]);
                    int idx = (int)(dv * HIST_INVW);
                    idx = idx < 0 ? 0 : (idx > NBINS - 1 ? NBINS - 1 : idx);
                    atomicAdd(&lhist[idx], 1u);
                }
            }
    });
    __syncthreads();
    unsigned* dst = hist8 + (size_t)((blockIdx.y * gridDim.x + blockIdx.x) & (NSHARD - 1)) * NBINS;
#pragma unroll
    for (int i = 0; i < NBINS / 256; ++i) {
        unsigned cv = lhist[t + i * 256];
        if (cv) atomicAdd(&dst[t + i * 256], cv);
    }
}

// Exp-write pass (R19 structure + XCD 2D-chunk swizzle): 512 blocks, 2
// column-tiles per block sharing X rows. Bijective block remap: xcd = id&7,
// w = id>>3; by = (xcd&3)*8 + (w&7), bx = (xcd>>2)*8 + (w>>3) — each XCD's
// 64 blocks form an 8x8 chunk (1024 X rows + 2048 Y cols ~ 0.75MB unique
// operands per XCD L2 instead of ~2.3MB). Local median recompute per block.
// Epilogue: full-tile LDS transpose, 16 wave-stores x 1KB contiguous, NT.
__launch_bounds__(256, 2)
__global__ void write_kernel(const unsigned short* __restrict__ Xh, const unsigned short* __restrict__ Xl,
                             const unsigned short* __restrict__ Yh, const unsigned short* __restrict__ Yl,
                             const float* __restrict__ x_sq, const float* __restrict__ y_sq,
                             const unsigned* __restrict__ hist8, float* __restrict__ out) {
    __shared__ float T[4][64][68];   // 69,632 B; per-wave 64x64 tile (scan aliases it)
    __shared__ float s_cc;
    const int t    = threadIdx.x;
    const int wave = t >> 6;
    const int lane = t & 63;
    const int fr = lane & 15;
    const int rb = (lane >> 4) * 4;
    const size_t la = (size_t)lane * 8;

    // XCD 2D-chunk swizzle (bijective on 512 = 8 xcd x 64):
    const int id  = blockIdx.x;
    const int xcd = id & 7;
    const int w   = id >> 3;                       // 0..63
    const int by  = (xcd & 3) * 8 + (w & 7);       // 0..31 row-strip
    const int bx  = (xcd >> 2) * 8 + (w >> 3);     // 0..15 col-strip
    const int i0  = by * 128 + (wave >> 1) * 64;
    const int j0b = bx * 256 + (wave & 1) * 64;

    {   // ---- local median: sum 8 shards (plain, coalesced, L2-broadcast),
        // scan in LDS (aliases T), derive cc. All blocks in parallel.
        unsigned* cnt  = (unsigned*)&T[0][0][0];   // 2048 u32
        unsigned* tsum = cnt + NBINS;              // 256 u32
        float*    vmed = (float*)(tsum + 256);     // 2 f32
        unsigned s = 0;
#pragma unroll
        for (int i = 0; i < NBINS / 256; ++i) {
            unsigned b = t * (NBINS / 256) + i;
            unsigned cv = 0;
#pragma unroll
            for (int sd = 0; sd < NSHARD; ++sd)
                cv += hist8[sd * NBINS + b];       // prior-kernel data: plain loads
            cnt[b] = cv;
            s += cv;
        }
        tsum[t] = s;
        __syncthreads();
        for (int off = 1; off < 256; off <<= 1) {
            unsigned v = (t >= off) ? tsum[t - off] : 0u;
            __syncthreads();
            tsum[t] += v;
            __syncthreads();
        }
        unsigned cum = (t == 0) ? 0u : tsum[t - 1];
        unsigned total = tsum[255];
        const unsigned K2 = total >> 1;            // torch median ranks
        const unsigned K1 = K2 - 1u + (total & 1u);
        for (int i = 0; i < NBINS / 256; ++i) {
            int b = t * (NBINS / 256) + i;
            unsigned cv = cnt[b];
            if (cv) {
                if (K1 >= cum && (K1 - cum) < cv)
                    vmed[0] = ((float)b + ((float)(K1 - cum) + 0.5f) / (float)cv) * HIST_W;
                if (K2 >= cum && (K2 - cum) < cv)
                    vmed[1] = ((float)b + ((float)(K2 - cum) + 0.5f) / (float)cv) * HIST_W;
            }
            cum += cv;
        }
        __syncthreads();
        if (t == 0) {
            double med   = 0.5 * ((double)vmed[0] + (double)vmed[1]);
            double gamma = 8.317766166719343 / med;               // ln(4096)/med
            s_cc = (float)(-gamma * 1.4426950408889634);          // -gamma*log2(e)
        }
        __syncthreads();   // s_cc ready; T free for tile reuse
    }
    const float cc = s_cc;

    const int pa0 = i0 >> 4;

    float xsv[4][4];
#pragma unroll
    for (int r = 0; r < 4; ++r)
#pragma unroll
        for (int q = 0; q < 4; ++q) xsv[r][q] = x_sq[i0 + r * 16 + rb + q];

    // X fragments: loaded ONCE, shared by both column-tiles.
    short8 fxh[8], fxl[8];
#pragma unroll
    for (int kh = 0; kh < 2; ++kh)
#pragma unroll
        for (int g = 0; g < 4; ++g) {
            const size_t ao = ((size_t)(pa0 + g) * 8 + kh * 4) * 128 + la;
            fxh[kh * 4 + g] = *(const short8*)(Xh + ao);
            fxl[kh * 4 + g] = *(const short8*)(Xl + ao);
        }

#pragma unroll 1
    for (int jt = 0; jt < 2; ++jt) {
        const int j0 = j0b + jt * 128;
        const int pb0 = j0 >> 4;

        short8 fyh[8], fyl[8];
#pragma unroll
        for (int kh = 0; kh < 2; ++kh)
#pragma unroll
            for (int g = 0; g < 4; ++g) {
                const size_t bo = ((size_t)(pb0 + g) * 8 + kh * 4) * 128 + la;
                fyh[kh * 4 + g] = *(const short8*)(Yh + bo);
                fyl[kh * 4 + g] = *(const short8*)(Yl + bo);
            }

        f32x4 acc[4][4];
#pragma unroll
        for (int r = 0; r < 4; ++r)
#pragma unroll
            for (int c = 0; c < 4; ++c) acc[r][c] = (f32x4){0.f, 0.f, 0.f, 0.f};
#pragma unroll
        for (int kh = 0; kh < 2; ++kh)
#pragma unroll
            for (int r = 0; r < 4; ++r)
#pragma unroll
                for (int c = 0; c < 4; ++c) {
                    acc[r][c] = __builtin_amdgcn_mfma_f32_16x16x32_bf16(fxh[kh * 4 + r], fyh[kh * 4 + c], acc[r][c], 0, 0, 0);
                    acc[r][c] = __builtin_amdgcn_mfma_f32_16x16x32_bf16(fxl[kh * 4 + r], fyh[kh * 4 + c], acc[r][c], 0, 0, 0);
                    acc[r][c] = __builtin_amdgcn_mfma_f32_16x16x32_bf16(fxh[kh * 4 + r], fyl[kh * 4 + c], acc[r][c], 0, 0, 0);
                    acc[r][c] = __builtin_amdgcn_mfma_f32_16x16x32_bf16(fxl[kh * 4 + r], fyl[kh * 4 + c], acc[r][c], 0, 0, 0);
                }

        float ysv[4];
#pragma unroll
        for (int c = 0; c < 4; ++c) ysv[c] = y_sq[j0 + c * 16 + fr];

        float* Tw = &T[wave][0][0];
        // scatter into LDS: T[row_local][col_local]; 2-way bank aliasing only (free)
#pragma unroll
        for (int r = 0; r < 4; ++r)
#pragma unroll
            for (int c = 0; c < 4; ++c)
#pragma unroll
                for (int q = 0; q < 4; ++q) {
                    float dv = fmaf(-2.f, acc[r][c][q], xsv[r][q] + ysv[c]);
                    Tw[(r * 16 + rb + q) * 68 + c * 16 + fr] = __builtin_amdgcn_exp2f(cc * dv);
                }
        // read rows back, store 256B-contiguous per row (full lines), NT.
#pragma unroll
        for (int ii = 0; ii < 16; ++ii) {
            int row = ii * 4 + (lane >> 4);
            f32x4 v = *(const f32x4*)&Tw[row * 68 + fr * 4];
            f32x4* po = (f32x4*)(out + (size_t)(i0 + row) * NROWS + j0 + fr * 4);
            __builtin_nontemporal_store(v, po);
        }
    }
}

extern "C" void kernel_launch(void* const* d_in, const int* in_sizes, int n_in,
                              void* d_out, int out_size, void* d_ws, size_t ws_size,
                              hipStream_t stream) {
    const float* X = (const float*)d_in[0];
    const float* Y = (const float*)d_in[1];
    float* out = (float*)d_out;

    unsigned* hist8    = (unsigned*)d_ws;
    float* x_sq        = (float*)((char*)d_ws + 65536);
    float* y_sq        = (float*)((char*)d_ws + 81920);
    unsigned short* Xh = (unsigned short*)((char*)d_ws + 131072);
    unsigned short* Xl = Xh + (size_t)NROWS * DDIM;
    unsigned short* Yh = Xl + (size_t)NROWS * DDIM;
    unsigned short* Yl = Yh + (size_t)NROWS * DDIM;

    prep_kernel<<<256, 256, 0, stream>>>(X, Y, Xh, Xl, Yh, Yl, x_sq, y_sq, hist8);
    hist_kernel<<<dim3(4, 32), 256, 0, stream>>>(Xh, Yh, x_sq, y_sq, hist8);
    write_kernel<<<512, 256, 0, stream>>>(Xh, Xl, Yh, Yl, x_sq, y_sq, hist8, out);
}